// Round 3
// baseline (307.423 us; speedup 1.0000x reference)
//
#include <hip/hip_runtime.h>
#include <cstdint>

#define NH 6
#define HD 32
#define NTOK 256
#define CIN 576
#define DIMO 192
#define LOG2E 1.44269504f
#define SHIFT2 37.6f
#define MNEG (-144.269504f)   // -100 * log2(e)

typedef short short8 __attribute__((ext_vector_type(8)));
typedef float f32x4 __attribute__((ext_vector_type(4)));
typedef int   int4v __attribute__((ext_vector_type(4)));

__device__ __forceinline__ int grp6(int x) { return (x < 48) ? 0 : ((x < 56) ? 1 : 2); }

__device__ __forceinline__ unsigned short f2bf(float f) {
    unsigned int u = __float_as_uint(f);
    u += 0x7fffu + ((u >> 16) & 1u);   // RTNE
    return (unsigned short)(u >> 16);
}

// Tile-linear swizzled offset (in shorts) for the Q/K fragment buffers.
// byte = tile*1024 + row*64 + (quad ^ ((row>>1)&3))*16
// Reads (row=l15, per-lane quad) form a 64x16B bijection over the 1KiB tile
// -> conflict-free ds_read_b128. Writes spread 8 lanes/bank-slot (optimal).
__device__ __forceinline__ int qk_off(int tile, int row, int quad) {
    return tile * 512 + row * 32 + ((quad ^ ((row >> 1) & 3)) << 3);
}

// window decode: same bijection as round 2 (id = r8 + 8*(j24 + 24*g8));
// persistent blocks use id = p + 512*it  (keeps id mod 8 -> same XCD residue)
struct Win { int b, wh, ww, h; };
__device__ __forceinline__ Win decode_win(int id) {
    int r8 = id & 7, q3 = id >> 3;        // q3: 0..191
    int j24 = q3 % 24, g8 = q3 / 24;
    int gg = r8 + 8 * g8;                 // 0..63 = b*4 + wh
    Win w;
    w.h  = j24 % 6;
    w.ww = j24 / 6;
    w.wh = gg & 3;
    w.b  = gg >> 2;
    return w;
}

// ---------------- kernel 1: CPB MLP (block per table point) ----------------
__global__ void cpb_kernel(const float* __restrict__ table,
                           const float* __restrict__ w1,
                           const float* __restrict__ b1,
                           const float* __restrict__ w2,
                           float* __restrict__ bv) {
    __shared__ float hid[512];
    int p = blockIdx.x;                 // 0..960
    float t0 = table[2 * p], t1 = table[2 * p + 1];
    int t = threadIdx.x;                // 256 threads
    for (int j = t; j < 512; j += 256) {
        float hv = fmaf(t0, w1[2 * j], fmaf(t1, w1[2 * j + 1], b1[j]));
        hid[j] = fmaxf(hv, 0.f);
    }
    __syncthreads();
    if (t < 192) {
        int h = t >> 5, l = t & 31;
        const float* w2h = w2 + h * 512;
        float acc = 0.f;
        for (int j = l; j < 512; j += 32) acc = fmaf(hid[j], w2h[j], acc);
        acc += __shfl_xor(acc, 1, 32);
        acc += __shfl_xor(acc, 2, 32);
        acc += __shfl_xor(acc, 4, 32);
        acc += __shfl_xor(acc, 8, 32);
        acc += __shfl_xor(acc, 16, 32);
        // fold -SHIFT2 into the bias grid
        if (l == 0) bv[h * 961 + p] = (16.f / (1.f + __expf(-acc))) * LOG2E - SHIFT2;
    }
}

// ---------------- kernel 2: persistent MFMA attention ----------------
// 512 blocks x 512 threads (2 blocks/CU), each block processes 3 windows.
// Software pipeline: while flash-computing window it, the q/k global loads of
// window it+1 are in flight into 32 pinned VGPRs (T14 async-STAGE at window
// granularity). v + Bv loads are issued at the top of stage, latency covered
// by the q/k norm VALU. All numerics identical to the previous round.
__global__ __launch_bounds__(512, 4) void attn_kernel(
    const float* __restrict__ qkv,
    const float* __restrict__ logit_scale,
    const float* __restrict__ bv,
    float* __restrict__ out)
{
    __shared__ __align__(16) short Qb[NTOK * HD];   // 16 KB  Q bf16, scale*log2e folded (tile-linear swizzled)
    __shared__ __align__(16) short Kb[NTOK * HD];   // 16 KB  K bf16 normalized (tile-linear swizzled)
    __shared__ __align__(16) short Vt[HD * 264];    // 16.9 KB V^T, stride 264, slot-permuted within 32-chunks
    __shared__ float Bv[961];                       // bias grid * log2e - SHIFT2

    const int t = threadIdx.x;
    const int n = t >> 1, s = t & 1;               // staging: 2 threads per token
    const int i = n >> 4, j = n & 15;              // tile, row-in-tile
    const int wv = t >> 6, lane = t & 63, quad = lane >> 4, l15 = lane & 15;
    const int trg0 = wv * 2, trg1 = wv * 2 + 1;

    Win W = decode_win(blockIdx.x);

    // prologue: issue window-0 q/k loads
    float4 pq[8];
    {
        const int rr = (W.wh * 16 + i + 8) & 63;
        const int cc = (W.ww * 16 + j + 8) & 63;
        const float4* p4 = (const float4*)(qkv + ((long)(W.b * 4096 + rr * 64 + cc)) * CIN + W.h * HD + s * DIMO);
#pragma unroll
        for (int w = 0; w < 8; ++w) pq[w] = p4[w];
    }

#pragma unroll 1
    for (int it = 0; it < 3; ++it) {
        // current window (saved: W is overwritten by the prefetch below)
        const int b = W.b, wh = W.wh, ww = W.ww, h = W.h;
        const float scale2 = __expf(fminf(logit_scale[h], 4.6051702f)) * LOG2E;

        // ---- stage current window ----
        const int rr = (wh * 16 + i + 8) & 63;
        const int cc = (ww * 16 + j + 8) & 63;
        const float* base = qkv + ((long)(b * 4096 + rr * 64 + cc)) * CIN + h * HD;

        // issue v loads first (latency hidden under q/k norm VALU below)
        float4 vr[4];
        {
            const float4* v4 = (const float4*)(base + 2 * DIMO + s * 16);
#pragma unroll
            for (int w = 0; w < 4; ++w) vr[w] = v4[w];
        }
        // bias grid for this head (L2-hot, 2 loads/thread)
        for (int q = t; q < 961; q += 512) Bv[q] = bv[h * 961 + q];

        // q/k: norm + scale + bf16 -> LDS (pq was prefetched)
        {
            float xv[32];
#pragma unroll
            for (int w = 0; w < 8; ++w) {
                xv[4 * w + 0] = pq[w].x; xv[4 * w + 1] = pq[w].y;
                xv[4 * w + 2] = pq[w].z; xv[4 * w + 3] = pq[w].w;
            }
            float a0 = 0.f, a1 = 0.f, a2 = 0.f, a3 = 0.f;
#pragma unroll
            for (int d = 0; d < 8; ++d) {
                a0 = fmaf(xv[d],      xv[d],      a0);
                a1 = fmaf(xv[d + 8],  xv[d + 8],  a1);
                a2 = fmaf(xv[d + 16], xv[d + 16], a2);
                a3 = fmaf(xv[d + 24], xv[d + 24], a3);
            }
            float ssum = (a0 + a1) + (a2 + a3);
            float sc = (s ? 1.f : scale2) / fmaxf(sqrtf(ssum), 1e-12f);
            short* dst = s ? Kb : Qb;
#pragma unroll
            for (int w = 0; w < 4; ++w) {
                short8 xc;
#pragma unroll
                for (int e = 0; e < 8; ++e) xc[e] = (short)f2bf(xv[8 * w + e] * sc);
                *(short8*)&dst[qk_off(i, j, w)] = xc;
            }
        }
        // V^T staging: col = chunk*32 + 2*brev4(pair) + (n&1)
        {
            float vv[16];
#pragma unroll
            for (int w = 0; w < 4; ++w) {
                vv[4 * w + 0] = vr[w].x; vv[4 * w + 1] = vr[w].y;
                vv[4 * w + 2] = vr[w].z; vv[4 * w + 3] = vr[w].w;
            }
            int u = (n >> 1) & 15;
            int jp = ((u & 1) << 3) | ((u & 2) << 1) | ((u & 4) >> 1) | ((u & 8) >> 3);
            int col = (n >> 5) * 32 + 2 * jp + (n & 1);
#pragma unroll
            for (int di = 0; di < 16; ++di) {
                int e = (di + 4 * s) & 15;           // s=1 rotated by 4 rows: bank sets 16 apart
                Vt[(s * 16 + e) * 264 + col] = (short)f2bf(vv[e]);
            }
        }
        __syncthreads();

        // ---- prefetch next window's q/k (in flight during flash) ----
        if (it < 2) {
            Win Wn = decode_win(blockIdx.x + 512 * (it + 1));
            const int rr2 = (Wn.wh * 16 + i + 8) & 63;
            const int cc2 = (Wn.ww * 16 + j + 8) & 63;
            const float4* p4 = (const float4*)(qkv + ((long)(Wn.b * 4096 + rr2 * 64 + cc2)) * CIN + Wn.h * HD + s * DIMO);
#pragma unroll
            for (int w = 0; w < 8; ++w) pq[w] = p4[w];
            W = Wn;
        }
        __builtin_amdgcn_sched_barrier(0);   // pin prefetch issue before flash

        // ---- flash loop ----
        short8 bQ[2];
        bQ[0] = *(const short8*)&Qb[qk_off(trg0, l15, quad)];
        bQ[1] = *(const short8*)&Qb[qk_off(trg1, l15, quad)];

        const int gqr[2] = {grp6(wh * 16 + trg0), grp6(wh * 16 + trg1)};
        const int gcl = grp6(ww * 16 + l15);
        float cm[4];
#pragma unroll
        for (int reg = 0; reg < 4; ++reg)
            cm[reg] = (gcl == grp6(ww * 16 + quad * 4 + reg)) ? 0.f : MNEG;

        f32x4 O[2][2];
        float lp[2] = {0.f, 0.f};
#pragma unroll
        for (int tl = 0; tl < 2; ++tl)
#pragma unroll
            for (int dtk = 0; dtk < 2; ++dtk) O[tl][dtk] = (f32x4){0.f, 0.f, 0.f, 0.f};

        const f32x4 Zero = (f32x4){0.f, 0.f, 0.f, 0.f};
        const int trg[2] = {trg0, trg1};

        for (int c = 0; c < 8; ++c) {
            int ctg[2] = {2 * c, 2 * c + 1};
            short8 aK[2], bV[2];
#pragma unroll
            for (int ct = 0; ct < 2; ++ct)
                aK[ct] = *(const short8*)&Kb[qk_off(ctg[ct], l15, quad)];
#pragma unroll
            for (int dtk = 0; dtk < 2; ++dtk)
                bV[dtk] = *(const short8*)&Vt[(dtk * 16 + l15) * 264 + c * 32 + quad * 8];

            int gkr[2] = {grp6(wh * 16 + ctg[0]), grp6(wh * 16 + ctg[1])};

#pragma unroll
            for (int tl = 0; tl < 2; ++tl) {
                // S^T = K * Q^T : lane holds S^T[key=ctg*16+quad*4+reg][q=trg*16+l15]
                f32x4 S0 = __builtin_amdgcn_mfma_f32_16x16x32_bf16(aK[0], bQ[tl], Zero, 0, 0, 0);
                f32x4 S1 = __builtin_amdgcn_mfma_f32_16x16x32_bf16(aK[1], bQ[tl], Zero, 0, 0, 0);

                float ev[2][4];
#pragma unroll
                for (int ct = 0; ct < 2; ++ct) {
                    const f32x4& Sc = ct ? S1 : S0;
                    int rb = (trg[tl] - ctg[ct] + 15) * 31 + 15 + l15 - 4 * quad;
                    bool rmatch = (gqr[tl] == gkr[ct]);       // wave-uniform
#pragma unroll
                    for (int reg = 0; reg < 4; ++reg) {
                        float madd = rmatch ? cm[reg] : MNEG;
                        float arg = Sc[reg] + (Bv[rb - reg] + madd);
                        float e = __builtin_amdgcn_exp2f(arg);
                        ev[ct][reg] = e;
                        lp[tl] += e;                          // row q = trg*16+l15
                    }
                }
                // pack to bf16 pairs; key-pairs: P0=(ct0 r4q,r4q+1) P1=(ct1 ...) P2=(ct0 r4q+2,+3) P3=(ct1 ...)
                int p0, p1, p2, p3;
                asm("v_cvt_pk_bf16_f32 %0, %1, %2" : "=v"(p0) : "v"(ev[0][0]), "v"(ev[0][1]));
                asm("v_cvt_pk_bf16_f32 %0, %1, %2" : "=v"(p1) : "v"(ev[1][0]), "v"(ev[1][1]));
                asm("v_cvt_pk_bf16_f32 %0, %1, %2" : "=v"(p2) : "v"(ev[0][2]), "v"(ev[0][3]));
                asm("v_cvt_pk_bf16_f32 %0, %1, %2" : "=v"(p3) : "v"(ev[1][2]), "v"(ev[1][3]));
                // exchange halves across lane<32 / lane>=32
                asm("v_permlane32_swap_b32 %0, %1" : "+v"(p0), "+v"(p2));
                asm("v_permlane32_swap_b32 %0, %1" : "+v"(p1), "+v"(p3));
                // A-fragment dwords [p0,p1,p2,p3]; key-slot->token map = brev4 of pair
                // index (same permutation baked into Vt staging above)
                int4v wd = {p0, p1, p2, p3};
                union { int4v iv; short8 sv; } cvt; cvt.iv = wd;
                short8 aP = cvt.sv;
                O[tl][0] = __builtin_amdgcn_mfma_f32_16x16x32_bf16(aP, bV[0], O[tl][0], 0, 0, 0);
                O[tl][1] = __builtin_amdgcn_mfma_f32_16x16x32_bf16(aP, bV[1], O[tl][1], 0, 0, 0);
            }
        }
        __syncthreads();   // flash LDS reads done; stores overlap next stage

        // ---- softmax denominator + store (window-reverse + unshift folded) ----
        const long pixb = (long)b * 4096;
#pragma unroll
        for (int tl = 0; tl < 2; ++tl) {
            float sm = lp[tl];
            sm += __shfl_xor(sm, 16);
            sm += __shfl_xor(sm, 32);
            float invf = 1.f / sm;                    // for q = trg*16 + l15
            int r = (wh * 16 + trg[tl] + 8) & 63;
#pragma unroll
            for (int reg = 0; reg < 4; ++reg) {
                float iv = __shfl(invf, quad * 4 + reg);   // row-sum for q = trg*16 + quad*4+reg
                int cpix = (ww * 16 + quad * 4 + reg + 8) & 63;
                float* op = out + (pixb + r * 64 + cpix) * DIMO + h * HD + l15;
                op[0]  = O[tl][0][reg] * iv;
                op[16] = O[tl][1][reg] * iv;
            }
        }
    }
}

extern "C" void kernel_launch(void* const* d_in, const int* in_sizes, int n_in,
                              void* d_out, int out_size, void* d_ws, size_t ws_size,
                              hipStream_t stream) {
    const float* qkv         = (const float*)d_in[0];
    const float* table       = (const float*)d_in[1];
    // d_in[2] = mask   : recomputed from window-region groups
    const float* logit_scale = (const float*)d_in[3];
    const float* w1          = (const float*)d_in[4];
    const float* b1          = (const float*)d_in[5];
    const float* w2          = (const float*)d_in[6];
    // d_in[7] = index  : recomputed from relative coords
    float* out = (float*)d_out;
    float* bv  = (float*)d_ws;   // 6*961 floats

    cpb_kernel<<<961, 256, 0, stream>>>(table, w1, b1, w2, bv);
    attn_kernel<<<512, 512, 0, stream>>>(qkv, logit_scale, bv, out);
}

// Round 4
// 275.606 us; speedup vs baseline: 1.1154x; 1.1154x over previous
//
#include <hip/hip_runtime.h>
#include <cstdint>

#define NH 6
#define HD 32
#define NTOK 256
#define CIN 576
#define DIMO 192
#define LOG2E 1.44269504f
#define SHIFT2 37.6f
#define MNEG (-144.269504f)   // -100 * log2(e)

typedef short short8 __attribute__((ext_vector_type(8)));
typedef float f32x4 __attribute__((ext_vector_type(4)));
typedef int   int4v __attribute__((ext_vector_type(4)));

__device__ __forceinline__ int grp6(int x) { return (x < 48) ? 0 : ((x < 56) ? 1 : 2); }

__device__ __forceinline__ unsigned short f2bf(float f) {
    unsigned int u = __float_as_uint(f);
    u += 0x7fffu + ((u >> 16) & 1u);   // RTNE
    return (unsigned short)(u >> 16);
}

// Tile-linear swizzled offset (in shorts) for the K fragment buffer.
// byte = tile*1024 + row*64 + (quad ^ ((row>>1)&3))*16
// Reads (row=l15, per-lane quad) form a 64x16B bijection over the 1KiB tile
// -> conflict-free ds_read_b128. Writes spread 8 lanes/bank-slot (optimal).
__device__ __forceinline__ int qk_off(int tile, int row, int quad) {
    return tile * 512 + row * 32 + ((quad ^ ((row >> 1) & 3)) << 3);
}

// ---------------- kernel 1: CPB MLP (block per table point) ----------------
__global__ void cpb_kernel(const float* __restrict__ table,
                           const float* __restrict__ w1,
                           const float* __restrict__ b1,
                           const float* __restrict__ w2,
                           float* __restrict__ bv) {
    __shared__ float hid[512];
    int p = blockIdx.x;                 // 0..960
    float t0 = table[2 * p], t1 = table[2 * p + 1];
    int t = threadIdx.x;                // 256 threads
    for (int j = t; j < 512; j += 256) {
        float hv = fmaf(t0, w1[2 * j], fmaf(t1, w1[2 * j + 1], b1[j]));
        hid[j] = fmaxf(hv, 0.f);
    }
    __syncthreads();
    if (t < 192) {
        int h = t >> 5, l = t & 31;
        const float* w2h = w2 + h * 512;
        float acc = 0.f;
        for (int j = l; j < 512; j += 32) acc = fmaf(hid[j], w2h[j], acc);
        acc += __shfl_xor(acc, 1, 32);
        acc += __shfl_xor(acc, 2, 32);
        acc += __shfl_xor(acc, 4, 32);
        acc += __shfl_xor(acc, 8, 32);
        acc += __shfl_xor(acc, 16, 32);
        // fold -SHIFT2 into the bias grid
        if (l == 0) bv[h * 961 + p] = (16.f / (1.f + __expf(-acc))) * LOG2E - SHIFT2;
    }
}

// ---------------- kernel 2: MFMA attention ----------------
// block = one (window, head), 512 threads = 8 waves; wave w owns q-rows [w*32, w*32+32)
// Occupancy-first layout: NO Q LDS buffer. Q has zero cross-wave reuse, so
// staging stores only a per-token scale Qn[256]; each flash lane re-reads its
// own 32B q-fragment from global (issued pre-barrier, L2-hot) and converts
// in-register with v_cvt_pk_bf16_f32 (bit-identical RTNE). LDS = 38.1 KB ->
// 4 blocks/CU resident (vs 3 at 52.5 KB), 32 waves/CU.
__global__ __launch_bounds__(512, 8) void attn_kernel(
    const float* __restrict__ qkv,
    const float* __restrict__ logit_scale,
    const float* __restrict__ bv,
    float* __restrict__ out)
{
    __shared__ __align__(16) short Kb[NTOK * HD];   // 16 KB  K bf16 normalized (tile-linear swizzled)
    __shared__ __align__(16) short Vt[HD * 264];    // 16.9 KB V^T, stride 264, slot-permuted within 32-chunks
    __shared__ float Bv[961];                       // bias grid * log2e - SHIFT2
    __shared__ float Qn[NTOK];                      // per-token q scale (scale2/||q||)

    const int t = threadIdx.x;
    const int h   = blockIdx.x % NH;
    const int win = blockIdx.x / NH;
    const int b = win >> 4, wl = win & 15, wh = wl >> 2, ww = wl & 3;

    const float scale2 = __expf(fminf(logit_scale[h], 4.6051702f)) * LOG2E;

    for (int p = t; p < 961; p += 512) Bv[p] = bv[h * 961 + p];

    // ---- balanced staging: 2 threads per token.
    //   s=0: q norm -> Qn (no pack/write);  s=1: k norm+pack -> Kb. both: half of V.
    {
        const int n = t >> 1, s = t & 1;
        const int i = n >> 4, j = n & 15;            // row-in-window, col-in-window
        const int rr = (wh * 16 + i + 8) & 63;
        const int cc = (ww * 16 + j + 8) & 63;
        const float* base = qkv + ((long)(b * 4096 + rr * 64 + cc)) * CIN + h * HD;

        // v half first (latency hidden under norm VALU)
        float4 vr[4];
        {
            const float4* v4 = (const float4*)(base + 2 * DIMO + s * 16);
#pragma unroll
            for (int w = 0; w < 4; ++w) vr[w] = v4[w];
        }
        // q (s=0) or k (s=1) stream
        float xv[32];
        {
            const float4* p4 = (const float4*)(base + s * DIMO);
#pragma unroll
            for (int w = 0; w < 8; ++w) {
                float4 x = p4[w];
                xv[4 * w + 0] = x.x; xv[4 * w + 1] = x.y; xv[4 * w + 2] = x.z; xv[4 * w + 3] = x.w;
            }
        }
        float a0 = 0.f, a1 = 0.f, a2 = 0.f, a3 = 0.f;
#pragma unroll
        for (int d = 0; d < 8; ++d) {
            a0 = fmaf(xv[d],      xv[d],      a0);
            a1 = fmaf(xv[d + 8],  xv[d + 8],  a1);
            a2 = fmaf(xv[d + 16], xv[d + 16], a2);
            a3 = fmaf(xv[d + 24], xv[d + 24], a3);
        }
        float ssum = (a0 + a1) + (a2 + a3);
        if (s == 0) {
            Qn[n] = scale2 / fmaxf(sqrtf(ssum), 1e-12f);
        } else {
            float sc = 1.f / fmaxf(sqrtf(ssum), 1e-12f);
#pragma unroll
            for (int w = 0; w < 4; ++w) {
                short8 xc;
#pragma unroll
                for (int e = 0; e < 8; ++e) xc[e] = (short)f2bf(xv[8 * w + e] * sc);
                *(short8*)&Kb[qk_off(i, j, w)] = xc;
            }
        }
        // V^T staging: col = chunk*32 + 2*brev4(pair) + (n&1)
        {
            float vv[16];
#pragma unroll
            for (int w = 0; w < 4; ++w) {
                vv[4 * w + 0] = vr[w].x; vv[4 * w + 1] = vr[w].y;
                vv[4 * w + 2] = vr[w].z; vv[4 * w + 3] = vr[w].w;
            }
            int u = (n >> 1) & 15;
            int jp = ((u & 1) << 3) | ((u & 2) << 1) | ((u & 4) >> 1) | ((u & 8) >> 3);
            int col = (n >> 5) * 32 + 2 * jp + (n & 1);
#pragma unroll
            for (int di = 0; di < 16; ++di) {
                int e = (di + 4 * s) & 15;           // s=1 rotated by 4 rows: bank sets 16 apart
                Vt[(s * 16 + e) * 264 + col] = (short)f2bf(vv[e]);
            }
        }
    }

    // ---- pre-barrier: issue this wave's q-fragment loads (L2-hot, no LDS dep)
    const int wv = t >> 6, lane = t & 63, quad = lane >> 4, l15 = lane & 15;
    float4 qfa[2], qfb[2];
#pragma unroll
    for (int tl = 0; tl < 2; ++tl) {
        int tok = wv * 32 + tl * 16 + l15;
        int ii = tok >> 4, jj = tok & 15;
        int rr2 = (wh * 16 + ii + 8) & 63;
        int cc2 = (ww * 16 + jj + 8) & 63;
        const float4* qp = (const float4*)(qkv + ((long)(b * 4096 + rr2 * 64 + cc2)) * CIN + h * HD + 8 * quad);
        qfa[tl] = qp[0];
        qfb[tl] = qp[1];
    }
    __syncthreads();

    // ---- build Q fragments in-register (RTNE, bit-identical to old LDS path)
    short8 bQ[2];
#pragma unroll
    for (int tl = 0; tl < 2; ++tl) {
        float qn = Qn[wv * 32 + tl * 16 + l15];
        float f0 = qfa[tl].x * qn, f1 = qfa[tl].y * qn, f2 = qfa[tl].z * qn, f3 = qfa[tl].w * qn;
        float f4 = qfb[tl].x * qn, f5 = qfb[tl].y * qn, f6 = qfb[tl].z * qn, f7 = qfb[tl].w * qn;
        int d0, d1, d2, d3;
        asm("v_cvt_pk_bf16_f32 %0, %1, %2" : "=v"(d0) : "v"(f0), "v"(f1));
        asm("v_cvt_pk_bf16_f32 %0, %1, %2" : "=v"(d1) : "v"(f2), "v"(f3));
        asm("v_cvt_pk_bf16_f32 %0, %1, %2" : "=v"(d2) : "v"(f4), "v"(f5));
        asm("v_cvt_pk_bf16_f32 %0, %1, %2" : "=v"(d3) : "v"(f6), "v"(f7));
        int4v wd = {d0, d1, d2, d3};
        union { int4v iv; short8 sv; } cvt; cvt.iv = wd;
        bQ[tl] = cvt.sv;
    }

    const int trg[2] = {wv * 2, wv * 2 + 1};
    const int gqr[2] = {grp6(wh * 16 + trg[0]), grp6(wh * 16 + trg[1])};
    const int gcl = grp6(ww * 16 + l15);        // q column-group: per-lane const
    float cm[4];
#pragma unroll
    for (int reg = 0; reg < 4; ++reg)
        cm[reg] = (gcl == grp6(ww * 16 + quad * 4 + reg)) ? 0.f : MNEG;

    f32x4 O[2][2];
    float lp[2] = {0.f, 0.f};
#pragma unroll
    for (int tl = 0; tl < 2; ++tl)
#pragma unroll
        for (int dtk = 0; dtk < 2; ++dtk) O[tl][dtk] = (f32x4){0.f, 0.f, 0.f, 0.f};

    const f32x4 Zero = (f32x4){0.f, 0.f, 0.f, 0.f};

    for (int c = 0; c < 8; ++c) {
        int ctg[2] = {2 * c, 2 * c + 1};
        short8 aK[2], bV[2];
#pragma unroll
        for (int ct = 0; ct < 2; ++ct)
            aK[ct] = *(const short8*)&Kb[qk_off(ctg[ct], l15, quad)];
#pragma unroll
        for (int dtk = 0; dtk < 2; ++dtk)
            bV[dtk] = *(const short8*)&Vt[(dtk * 16 + l15) * 264 + c * 32 + quad * 8];

        // S^T = K * Q^T : lane holds S^T[key=ctg*16+quad*4+reg][q=trg*16+l15]
        f32x4 S[2][2];
#pragma unroll
        for (int tl = 0; tl < 2; ++tl)
#pragma unroll
            for (int ct = 0; ct < 2; ++ct)
                S[tl][ct] = __builtin_amdgcn_mfma_f32_16x16x32_bf16(aK[ct], bQ[tl], Zero, 0, 0, 0);

        int gkr[2] = {grp6(wh * 16 + ctg[0]), grp6(wh * 16 + ctg[1])};

#pragma unroll
        for (int tl = 0; tl < 2; ++tl) {
            float ev[2][4];
#pragma unroll
            for (int ct = 0; ct < 2; ++ct) {
                int rb = (trg[tl] - ctg[ct] + 15) * 31 + 15 + l15 - 4 * quad;
                bool rmatch = (gqr[tl] == gkr[ct]);       // wave-uniform
#pragma unroll
                for (int reg = 0; reg < 4; ++reg) {
                    float madd = rmatch ? cm[reg] : MNEG;
                    float arg = S[tl][ct][reg] + (Bv[rb - reg] + madd);
                    float e = __builtin_amdgcn_exp2f(arg);
                    ev[ct][reg] = e;
                    lp[tl] += e;                          // row q = trg*16+l15
                }
            }
            // pack to bf16 pairs; key-pairs: P0=(ct0 r4q,r4q+1) P1=(ct1 ...) P2=(ct0 r4q+2,+3) P3=(ct1 ...)
            int p0, p1, p2, p3;
            asm("v_cvt_pk_bf16_f32 %0, %1, %2" : "=v"(p0) : "v"(ev[0][0]), "v"(ev[0][1]));
            asm("v_cvt_pk_bf16_f32 %0, %1, %2" : "=v"(p1) : "v"(ev[1][0]), "v"(ev[1][1]));
            asm("v_cvt_pk_bf16_f32 %0, %1, %2" : "=v"(p2) : "v"(ev[0][2]), "v"(ev[0][3]));
            asm("v_cvt_pk_bf16_f32 %0, %1, %2" : "=v"(p3) : "v"(ev[1][2]), "v"(ev[1][3]));
            // exchange halves across lane<32 / lane>=32
            asm("v_permlane32_swap_b32 %0, %1" : "+v"(p0), "+v"(p2));
            asm("v_permlane32_swap_b32 %0, %1" : "+v"(p1), "+v"(p3));
            // A-fragment dwords [p0,p1,p2,p3]; key-slot->token map = brev4 of pair
            // index (same permutation baked into Vt staging above)
            int4v wd = {p0, p1, p2, p3};
            union { int4v iv; short8 sv; } cvt; cvt.iv = wd;
            short8 aP = cvt.sv;
            O[tl][0] = __builtin_amdgcn_mfma_f32_16x16x32_bf16(aP, bV[0], O[tl][0], 0, 0, 0);
            O[tl][1] = __builtin_amdgcn_mfma_f32_16x16x32_bf16(aP, bV[1], O[tl][1], 0, 0, 0);
        }
    }

    // ---- softmax denominator: reduce across quads, then gather per output row
    const long pixb = (long)b * 4096;
#pragma unroll
    for (int tl = 0; tl < 2; ++tl) {
        float s = lp[tl];
        s += __shfl_xor(s, 16);
        s += __shfl_xor(s, 32);
        float invf = 1.f / s;                     // for q = trg*16 + l15
        int r = (wh * 16 + trg[tl] + 8) & 63;
#pragma unroll
        for (int reg = 0; reg < 4; ++reg) {
            float iv = __shfl(invf, quad * 4 + reg);   // row-sum for q = trg*16 + quad*4+reg
            int cpix = (ww * 16 + quad * 4 + reg + 8) & 63;
            float* op = out + (pixb + r * 64 + cpix) * DIMO + h * HD + l15;
            op[0]  = O[tl][0][reg] * iv;
            op[16] = O[tl][1][reg] * iv;
        }
    }
}

extern "C" void kernel_launch(void* const* d_in, const int* in_sizes, int n_in,
                              void* d_out, int out_size, void* d_ws, size_t ws_size,
                              hipStream_t stream) {
    const float* qkv         = (const float*)d_in[0];
    const float* table       = (const float*)d_in[1];
    // d_in[2] = mask   : recomputed from window-region groups
    const float* logit_scale = (const float*)d_in[3];
    const float* w1          = (const float*)d_in[4];
    const float* b1          = (const float*)d_in[5];
    const float* w2          = (const float*)d_in[6];
    // d_in[7] = index  : recomputed from relative coords
    float* out = (float*)d_out;
    float* bv  = (float*)d_ws;   // 6*961 floats

    cpb_kernel<<<961, 256, 0, stream>>>(table, w1, b1, w2, bv);
    attn_kernel<<<256 * NH, 512, 0, stream>>>(qkv, logit_scale, bv, out);
}

// Round 5
// 259.781 us; speedup vs baseline: 1.1834x; 1.0609x over previous
//
#include <hip/hip_runtime.h>
#include <cstdint>

#define NH 6
#define HD 32
#define NTOK 256
#define CIN 576
#define DIMO 192
#define LOG2E 1.44269504f
#define SHIFT2 37.6f
#define MNEG (-144.269504f)   // -100 * log2(e)

typedef short short8 __attribute__((ext_vector_type(8)));
typedef float f32x4 __attribute__((ext_vector_type(4)));
typedef int   int4v __attribute__((ext_vector_type(4)));

__device__ __forceinline__ int grp6(int x) { return (x < 48) ? 0 : ((x < 56) ? 1 : 2); }

__device__ __forceinline__ unsigned short f2bf(float f) {
    unsigned int u = __float_as_uint(f);
    u += 0x7fffu + ((u >> 16) & 1u);   // RTNE
    return (unsigned short)(u >> 16);
}

// pack two f32 -> one dword of 2 bf16 (RTNE, bit-identical to f2bf pair)
__device__ __forceinline__ int pkbf(float lo, float hi) {
    int r;
    asm("v_cvt_pk_bf16_f32 %0, %1, %2" : "=v"(r) : "v"(lo), "v"(hi));
    return r;
}

// Tile-linear swizzled offset (in shorts) for the Q/K fragment buffers.
// byte = tile*1024 + row*64 + (quad ^ ((row>>1)&3))*16
// Reads (row=l15, per-lane quad) form a 64x16B bijection over the 1KiB tile
// -> conflict-free ds_read_b128. Writes spread 8 lanes/bank-slot (optimal).
__device__ __forceinline__ int qk_off(int tile, int row, int quad) {
    return tile * 512 + row * 32 + ((quad ^ ((row >> 1) & 3)) << 3);
}

// ---------------- kernel 1: CPB MLP (block per table point) ----------------
__global__ void cpb_kernel(const float* __restrict__ table,
                           const float* __restrict__ w1,
                           const float* __restrict__ b1,
                           const float* __restrict__ w2,
                           float* __restrict__ bv) {
    __shared__ float hid[512];
    int p = blockIdx.x;                 // 0..960
    float t0 = table[2 * p], t1 = table[2 * p + 1];
    int t = threadIdx.x;                // 256 threads
    for (int j = t; j < 512; j += 256) {
        float hv = fmaf(t0, w1[2 * j], fmaf(t1, w1[2 * j + 1], b1[j]));
        hid[j] = fmaxf(hv, 0.f);
    }
    __syncthreads();
    if (t < 192) {
        int h = t >> 5, l = t & 31;
        const float* w2h = w2 + h * 512;
        float acc = 0.f;
        for (int j = l; j < 512; j += 32) acc = fmaf(hid[j], w2h[j], acc);
        acc += __shfl_xor(acc, 1, 32);
        acc += __shfl_xor(acc, 2, 32);
        acc += __shfl_xor(acc, 4, 32);
        acc += __shfl_xor(acc, 8, 32);
        acc += __shfl_xor(acc, 16, 32);
        // fold -SHIFT2 into the bias grid
        if (l == 0) bv[h * 961 + p] = (16.f / (1.f + __expf(-acc))) * LOG2E - SHIFT2;
    }
}

// ---------------- kernel 2: MFMA attention ----------------
// block = one (window, head), 512 threads = 8 waves; wave w owns q-rows [w*32, w*32+32)
// Swapped QK^T (S^T = mfma(K,Q)): each lane's q-row is lane-local (q_c = l15),
// P transposed to the PV A-fragment IN REGISTERS via v_cvt_pk_bf16_f32 +
// v_permlane32_swap_b32 (no LDS P buffer). The induced key-slot permutation
// (bit-reversal of key-pair index within each 32-key chunk) is folded into
// the V LDS layout at staging time. Staging packs use v_cvt_pk_bf16_f32
// (1 instr / 2 elems) instead of scalar f2bf (~3 instr / elem).
__global__ __launch_bounds__(512, 4) void attn_kernel(
    const float* __restrict__ qkv,
    const float* __restrict__ logit_scale,
    const float* __restrict__ bv,
    float* __restrict__ out)
{
    __shared__ __align__(16) short Qb[NTOK * HD];   // 16 KB  Q bf16, scale*log2e folded (tile-linear swizzled)
    __shared__ __align__(16) short Kb[NTOK * HD];   // 16 KB  K bf16 normalized (tile-linear swizzled)
    __shared__ __align__(16) short Vt[HD * 264];    // 16.9 KB V^T, stride 264, slot-permuted within 32-chunks
    __shared__ float Bv[961];                       // bias grid * log2e - SHIFT2

    const int t = threadIdx.x;
    const int h = blockIdx.x % NH;
    const int win = blockIdx.x / NH;
    const int b = win >> 4, wl = win & 15, wh = wl >> 2, ww = wl & 3;

    const float scale2 = __expf(fminf(logit_scale[h], 4.6051702f)) * LOG2E;

    for (int p = t; p < 961; p += 512) Bv[p] = bv[h * 961 + p];

    // ---- staging: threads 0..255 do Q,K; 256..511 do V^T
    {
        int n = (t < 256) ? t : (t - 256);
        int i = n >> 4, j = n & 15;
        int rr = wh * 16 + i, cc = ww * 16 + j;
        int r = (rr + 8) & 63, c = (cc + 8) & 63;
        const float* base = qkv + ((long)(b * 4096 + r * 64 + c)) * CIN + h * HD;
        if (t < 256) {
            float qv[32], kv[32];
            const float4* qp = (const float4*)base;
            const float4* kp = (const float4*)(base + DIMO);
#pragma unroll
            for (int w = 0; w < 8; ++w) {
                float4 x = qp[w];
                qv[4 * w + 0] = x.x; qv[4 * w + 1] = x.y; qv[4 * w + 2] = x.z; qv[4 * w + 3] = x.w;
            }
#pragma unroll
            for (int w = 0; w < 8; ++w) {
                float4 x = kp[w];
                kv[4 * w + 0] = x.x; kv[4 * w + 1] = x.y; kv[4 * w + 2] = x.z; kv[4 * w + 3] = x.w;
            }
            float sq = 0.f, sk = 0.f;
#pragma unroll
            for (int d = 0; d < 32; ++d) { sq = fmaf(qv[d], qv[d], sq); sk = fmaf(kv[d], kv[d], sk); }
            float qs = scale2 / fmaxf(sqrtf(sq), 1e-12f);
            float ks = 1.f / fmaxf(sqrtf(sk), 1e-12f);
#pragma unroll
            for (int w = 0; w < 4; ++w) {
                int4v qd, kd;
#pragma unroll
                for (int e = 0; e < 4; ++e) {
                    qd[e] = pkbf(qv[8 * w + 2 * e] * qs, qv[8 * w + 2 * e + 1] * qs);
                    kd[e] = pkbf(kv[8 * w + 2 * e] * ks, kv[8 * w + 2 * e + 1] * ks);
                }
                union { int4v iv; short8 sv; } cq, ck;
                cq.iv = qd; ck.iv = kd;
                int off = qk_off(i, j, w);
                *(short8*)&Qb[off] = cq.sv;
                *(short8*)&Kb[off] = ck.sv;
            }
        } else {
            float va[16], vb[16];
            {
                int ja = n & 15;                 // even token col within tile row handled below
                // n indexes token-pairs: tokens (2n, 2n+1) -> same tile row pair
            }
            // V: thread handles tokens (2m, 2m+1), all 32 d? No: R1 scheme = token pair x d-half
            int m = n & 127, dh = n >> 7;
            int i2 = m >> 3;                     // (2m)>>4
            int ja = (2 * m) & 15;               // even
            int r2 = (wh * 16 + i2 + 8) & 63;
            int ca = (ww * 16 + ja + 8) & 63;
            int cb = (ww * 16 + ja + 1 + 8) & 63;
            const float* ba = qkv + ((long)(b * 4096 + r2 * 64 + ca)) * CIN + h * HD + 2 * DIMO + dh * 16;
            const float* bb = qkv + ((long)(b * 4096 + r2 * 64 + cb)) * CIN + h * HD + 2 * DIMO + dh * 16;
            const float4* pa4 = (const float4*)ba;
            const float4* pb4 = (const float4*)bb;
#pragma unroll
            for (int w = 0; w < 4; ++w) {
                float4 A = pa4[w], B = pb4[w];
                va[4 * w + 0] = A.x; va[4 * w + 1] = A.y; va[4 * w + 2] = A.z; va[4 * w + 3] = A.w;
                vb[4 * w + 0] = B.x; vb[4 * w + 1] = B.y; vb[4 * w + 2] = B.z; vb[4 * w + 3] = B.w;
            }
            // slot-pair = brev4(token-pair index within 32-chunk)
            int u = m & 15;
            int jp = ((u & 1) << 3) | ((u & 2) << 1) | ((u & 4) >> 1) | ((u & 8) >> 3);
            int colb = (m >> 4) * 32 + 2 * jp;
#pragma unroll
            for (int di = 0; di < 16; ++di) {
                int pw = pkbf(va[di], vb[di]);   // lo = token 2m, hi = token 2m+1
                *(int*)&Vt[(dh * 16 + di) * 264 + colb] = pw;
            }
        }
    }
    __syncthreads();

    // ---- per-wave MFMA flash loop
    const int wv = t >> 6, lane = t & 63, quad = lane >> 4, l15 = lane & 15;

    int trg[2] = {wv * 2, wv * 2 + 1};
    short8 bQ[2];
#pragma unroll
    for (int tl = 0; tl < 2; ++tl)
        bQ[tl] = *(const short8*)&Qb[qk_off(trg[tl], l15, quad)];

    int gqr[2];
#pragma unroll
    for (int tl = 0; tl < 2; ++tl) gqr[tl] = grp6(wh * 16 + trg[tl]);
    const int gcl = grp6(ww * 16 + l15);        // q column-group: per-lane const
    float cm[4];
#pragma unroll
    for (int reg = 0; reg < 4; ++reg)
        cm[reg] = (gcl == grp6(ww * 16 + quad * 4 + reg)) ? 0.f : MNEG;

    f32x4 O[2][2];
    float lp[2] = {0.f, 0.f};
#pragma unroll
    for (int tl = 0; tl < 2; ++tl)
#pragma unroll
        for (int dtk = 0; dtk < 2; ++dtk) O[tl][dtk] = (f32x4){0.f, 0.f, 0.f, 0.f};

    const f32x4 Zero = (f32x4){0.f, 0.f, 0.f, 0.f};

    for (int c = 0; c < 8; ++c) {
        int ctg[2] = {2 * c, 2 * c + 1};
        short8 aK[2], bV[2];
#pragma unroll
        for (int ct = 0; ct < 2; ++ct)
            aK[ct] = *(const short8*)&Kb[qk_off(ctg[ct], l15, quad)];
#pragma unroll
        for (int dtk = 0; dtk < 2; ++dtk)
            bV[dtk] = *(const short8*)&Vt[(dtk * 16 + l15) * 264 + c * 32 + quad * 8];

        // S^T = K * Q^T : lane holds S^T[key=ctg*16+quad*4+reg][q=trg*16+l15]
        f32x4 S[2][2];
#pragma unroll
        for (int tl = 0; tl < 2; ++tl)
#pragma unroll
            for (int ct = 0; ct < 2; ++ct)
                S[tl][ct] = __builtin_amdgcn_mfma_f32_16x16x32_bf16(aK[ct], bQ[tl], Zero, 0, 0, 0);

        int gkr[2] = {grp6(wh * 16 + ctg[0]), grp6(wh * 16 + ctg[1])};

#pragma unroll
        for (int tl = 0; tl < 2; ++tl) {
            float ev[2][4];
#pragma unroll
            for (int ct = 0; ct < 2; ++ct) {
                int rb = (trg[tl] - ctg[ct] + 15) * 31 + 15 + l15 - 4 * quad;
                bool rmatch = (gqr[tl] == gkr[ct]);       // wave-uniform
#pragma unroll
                for (int reg = 0; reg < 4; ++reg) {
                    float madd = rmatch ? cm[reg] : MNEG;
                    float arg = S[tl][ct][reg] + (Bv[rb - reg] + madd);
                    float e = __builtin_amdgcn_exp2f(arg);
                    ev[ct][reg] = e;
                    lp[tl] += e;                          // row q = trg*16+l15
                }
            }
            // pack to bf16 pairs; key-pairs: P0=(ct0 r4q,r4q+1) P1=(ct1 ...) P2=(ct0 r4q+2,+3) P3=(ct1 ...)
            int p0 = pkbf(ev[0][0], ev[0][1]);
            int p1 = pkbf(ev[1][0], ev[1][1]);
            int p2 = pkbf(ev[0][2], ev[0][3]);
            int p3 = pkbf(ev[1][2], ev[1][3]);
            // exchange halves across lane<32 / lane>=32
            asm("v_permlane32_swap_b32 %0, %1" : "+v"(p0), "+v"(p2));
            asm("v_permlane32_swap_b32 %0, %1" : "+v"(p1), "+v"(p3));
            // A-fragment dwords [p0,p1,p2,p3]; key-slot->token map = brev4 of pair
            // index (same permutation baked into Vt staging above)
            int4v wd = {p0, p1, p2, p3};
            union { int4v iv; short8 sv; } cvt; cvt.iv = wd;
            short8 aP = cvt.sv;
            O[tl][0] = __builtin_amdgcn_mfma_f32_16x16x32_bf16(aP, bV[0], O[tl][0], 0, 0, 0);
            O[tl][1] = __builtin_amdgcn_mfma_f32_16x16x32_bf16(aP, bV[1], O[tl][1], 0, 0, 0);
        }
    }

    // ---- softmax denominator: reduce across quads, then gather per output row
    const long pixb = (long)b * 4096;
#pragma unroll
    for (int tl = 0; tl < 2; ++tl) {
        float s = lp[tl];
        s += __shfl_xor(s, 16);
        s += __shfl_xor(s, 32);
        float invf = 1.f / s;                     // for q = trg*16 + l15
        int r = (wh * 16 + trg[tl] + 8) & 63;
#pragma unroll
        for (int reg = 0; reg < 4; ++reg) {
            float iv = __shfl(invf, quad * 4 + reg);   // row-sum for q = trg*16 + quad*4+reg
            int cpix = (ww * 16 + quad * 4 + reg + 8) & 63;
            float* op = out + (pixb + r * 64 + cpix) * DIMO + h * HD + l15;
            op[0]  = O[tl][0][reg] * iv;
            op[16] = O[tl][1][reg] * iv;
        }
    }
}

extern "C" void kernel_launch(void* const* d_in, const int* in_sizes, int n_in,
                              void* d_out, int out_size, void* d_ws, size_t ws_size,
                              hipStream_t stream) {
    const float* qkv         = (const float*)d_in[0];
    const float* table       = (const float*)d_in[1];
    // d_in[2] = mask   : recomputed from window-region groups
    const float* logit_scale = (const float*)d_in[3];
    const float* w1          = (const float*)d_in[4];
    const float* b1          = (const float*)d_in[5];
    const float* w2          = (const float*)d_in[6];
    // d_in[7] = index  : recomputed from relative coords
    float* out = (float*)d_out;
    float* bv  = (float*)d_ws;   // 6*961 floats

    cpb_kernel<<<961, 256, 0, stream>>>(table, w1, b1, w2, bv);
    attn_kernel<<<256 * NH, 512, 0, stream>>>(qkv, logit_scale, bv, out);
}